// Round 2
// baseline (30442.368 us; speedup 1.0000x reference)
//
#include <hip/hip_runtime.h>

typedef unsigned short u16;
typedef short v8s __attribute__((ext_vector_type(8)));
typedef float v4f __attribute__((ext_vector_type(4)));

#define T_ 512
#define B_ 512
#define I_ 128
#define H_ 512
#define KK 640
#define NSTEP 512

__device__ inline u16 f2b(float x){
  union{float f; unsigned u;} v; v.f = x;
  unsigned r = v.u + 0x7fffu + ((v.u >> 16) & 1u);
  return (u16)(r >> 16);
}

__device__ inline unsigned ld_acq(const unsigned* p){
  return __hip_atomic_load(p, __ATOMIC_ACQUIRE, __HIP_MEMORY_SCOPE_AGENT);
}
__device__ inline void arrive(unsigned* p){
  __threadfence();
  __hip_atomic_fetch_add(p, 1u, __ATOMIC_RELEASE, __HIP_MEMORY_SCOPE_AGENT);
}

// Prep: Wcat[gcol][k] = [W_hh (k<512) | W_ih (k>=512)] bf16 (out-part LAST so the
// feedback-dependent staging can be deferred), fcW bf16, fused bias, h0 bf16,
// out0 = x[511] bf16, and zeroed sync counters.
__global__ void init_kernel(const float* __restrict__ x, const float* __restrict__ h0,
    const float* __restrict__ Wih, const float* __restrict__ Whh,
    const float* __restrict__ bih, const float* __restrict__ bhh, const float* __restrict__ fcW,
    u16* __restrict__ Wcat, u16* __restrict__ fcWb, float* __restrict__ bsum,
    u16* __restrict__ hb0, u16* __restrict__ outb, unsigned* __restrict__ flags)
{
  int idx = blockIdx.x * 256 + threadIdx.x;
  if (idx < 1310720) {                       // Wcat: 2048 x 640, [Whh | Wih]
    int g = idx / 640, k = idx - g * 640;
    float v = (k < 512) ? Whh[g * 512 + k] : Wih[g * 128 + (k - 512)];
    Wcat[idx] = f2b(v);
  } else if (idx < 1376256) {                // fcW bf16: 128 x 512
    int i = idx - 1310720; fcWb[i] = f2b(fcW[i]);
  } else if (idx < 1378304) {                // fused bias: 2048
    int i = idx - 1376256; bsum[i] = bih[i] + bhh[i];
  } else if (idx < 1640448) {                // h init: 512 x 512
    int i = idx - 1378304; hb0[i] = f2b(h0[i]);
  } else if (idx < 1705984) {                // inp init = x[511]: 512 x 128
    int i = idx - 1640448; outb[i] = f2b(x[33488896 + i]);
  } else if (idx < 1706000) {                // cnt[8] + out_cnt[8]
    flags[idx - 1705984] = 0u;
  }
}

// Persistent decoder. 288 wgs: wg<256 = gates/cell (mb=wg>>5 owns rows mb*64..+64,
// nb=wg&31 owns h-cols nb*16..+16 across all 4 gates; wave g = gate g).
// wg>=256 = fc (4 per mb group, 32 i-cols each), overlapped with next step's gates.
// Sync: per-group monotonic counters cnt[mb] (32 arrivals/step) and out_cnt[mb]
// (4 fc arrivals/step), device-scope acquire/release. c lives in VGPRs.
// W B-fragments are step-invariant -> preloaded into 80 VGPRs before the t-loop.
__global__ __launch_bounds__(256, 2) void decoder_persist(
    const u16* __restrict__ Wcat, const float* __restrict__ bsum,
    const u16* __restrict__ fcWb, const float* __restrict__ fcb,
    const float* __restrict__ c0,
    u16* __restrict__ hb0, u16* __restrict__ hb1, u16* __restrict__ outb,
    float* __restrict__ dout, unsigned* __restrict__ flags)
{
  const int tid  = threadIdx.x;
  const int wave = tid >> 6, lane = tid & 63;
  const int n16  = lane & 15, q = lane >> 4;
  unsigned* cnt     = flags;
  unsigned* out_cnt = flags + 8;

  if (blockIdx.x < 256) {
    // ---------------- gates + cell path ----------------
    __shared__ u16  Alds[64 * 328];          // one 320-k half, pad->stride 328 (2-way free)
    __shared__ float gbuf[4 * 64 * 16];      // gate exchange

    const int mb = blockIdx.x >> 5, nb = blockIdx.x & 31;
    const int R  = mb * 64;
    unsigned* mycnt = cnt + mb;
    unsigned* myout = out_cnt + mb;

    // Step-invariant W fragments: k = kc*32 + q*8, kc in [0,20)
    const u16* wrow = Wcat + (wave * 512 + nb * 16 + n16) * KK + q * 8;
    v8s bfrag[20];
    #pragma unroll
    for (int kc = 0; kc < 20; ++kc)
      bfrag[kc] = *reinterpret_cast<const v8s*>(wrow + kc * 32);

    const float bias = bsum[wave * 512 + nb * 16 + n16];

    // c state in registers: element e = j*256+tid -> (row=e>>4, col=e&15)
    float c[4];
    #pragma unroll
    for (int j = 0; j < 4; ++j) {
      int e = j * 256 + tid;
      c[j] = c0[(R + (e >> 4)) * H_ + nb * 16 + (e & 15)];
    }

    for (int t = 0; t < NSTEP; ++t) {
      const u16* hin  = (t & 1) ? hb1 : hb0;
      u16*       hout = (t & 1) ? hb0 : hb1;

      if (t > 0) {                            // group barrier: h(t) fully written
        if (tid == 0) while (ld_acq(mycnt) < (unsigned)(32 * t)) {}
        __syncthreads();
      }

      v4f acc[4];
      #pragma unroll
      for (int m = 0; m < 4; ++m) acc[m] = (v4f){0.f, 0.f, 0.f, 0.f};

      // ---- half 1: k in [0,320) -- all from h ----
      for (int j = 0; j < 10; ++j) {
        int v = j * 256 + tid;
        int row = v / 40, cc = v - row * 40;
        v8s val = *reinterpret_cast<const v8s*>(hin + (R + row) * H_ + cc * 8);
        *reinterpret_cast<v8s*>(&Alds[row * 328 + cc * 8]) = val;
      }
      __syncthreads();
      #pragma unroll
      for (int kc = 0; kc < 10; ++kc) {
        int k0 = kc * 32 + q * 8;
        #pragma unroll
        for (int m = 0; m < 4; ++m) {
          v8s a = *reinterpret_cast<const v8s*>(&Alds[(m * 16 + n16) * 328 + k0]);
          acc[m] = __builtin_amdgcn_mfma_f32_16x16x32_bf16(a, bfrag[kc], acc[m], 0, 0, 0);
        }
      }
      __syncthreads();                        // half-1 reads done, buffer reusable

      // ---- half 2a: k in [320,512) (h part, local chunks 0..23) ----
      for (int j = 0; j < 6; ++j) {
        int v = j * 256 + tid;
        int row = v / 24, cc = v - row * 24;
        v8s val = *reinterpret_cast<const v8s*>(hin + (R + row) * H_ + 320 + cc * 8);
        *reinterpret_cast<v8s*>(&Alds[row * 328 + cc * 8]) = val;
      }
      __syncthreads();
      #pragma unroll
      for (int kc = 0; kc < 6; ++kc) {
        int k0 = kc * 32 + q * 8;
        #pragma unroll
        for (int m = 0; m < 4; ++m) {
          v8s a = *reinterpret_cast<const v8s*>(&Alds[(m * 16 + n16) * 328 + k0]);
          acc[m] = __builtin_amdgcn_mfma_f32_16x16x32_bf16(a, bfrag[10 + kc], acc[m], 0, 0, 0);
        }
      }

      // ---- half 2b: out part k in [512,640) (local chunks 24..39) ----
      if (tid == 0) while (ld_acq(myout) < (unsigned)(4 * t)) {}   // out(t) ready
      __syncthreads();
      for (int j = 0; j < 4; ++j) {
        int v = j * 256 + tid;
        int row = v >> 4, cc = v & 15;
        v8s val = *reinterpret_cast<const v8s*>(outb + (R + row) * I_ + cc * 8);
        *reinterpret_cast<v8s*>(&Alds[row * 328 + (24 + cc) * 8]) = val;
      }
      __syncthreads();
      #pragma unroll
      for (int kc = 6; kc < 10; ++kc) {
        int k0 = kc * 32 + q * 8;
        #pragma unroll
        for (int m = 0; m < 4; ++m) {
          v8s a = *reinterpret_cast<const v8s*>(&Alds[(m * 16 + n16) * 328 + k0]);
          acc[m] = __builtin_amdgcn_mfma_f32_16x16x32_bf16(a, bfrag[10 + kc], acc[m], 0, 0, 0);
        }
      }

      // ---- activations -> LDS exchange ----
      #pragma unroll
      for (int m = 0; m < 4; ++m) {
        #pragma unroll
        for (int r = 0; r < 4; ++r) {
          float z = acc[m][r] + bias;
          float a = (wave == 2) ? tanhf(z) : 1.f / (1.f + __expf(-z));
          gbuf[wave * 1024 + (m * 16 + q * 4 + r) * 16 + n16] = a;
        }
      }
      __syncthreads();

      // ---- cell update: c in regs, h_new -> global (double-buffered) ----
      #pragma unroll
      for (int j = 0; j < 4; ++j) {
        int e = j * 256 + tid;
        int row = e >> 4, col = e & 15;
        float ig = gbuf[          row * 16 + col];
        float fg = gbuf[1024 +    row * 16 + col];
        float gg = gbuf[2048 +    row * 16 + col];
        float og = gbuf[3072 +    row * 16 + col];
        float cn = fg * c[j] + ig * gg;
        c[j] = cn;
        hout[(R + row) * H_ + nb * 16 + col] = f2b(og * tanhf(cn));
      }
      __syncthreads();                        // all cell writes issued before arrive
      if (tid == 0) arrive(mycnt);
    }
  } else {
    // ---------------- fc path (overlapped) ----------------
    const int f  = blockIdx.x - 256;
    const int mb = f >> 2, fq = f & 3;
    const int R  = mb * 64;
    unsigned* mycnt = cnt + mb;
    unsigned* myout = out_cnt + mb;

    const u16* b0 = fcWb + (fq * 32 + n16) * H_;
    const u16* b1 = b0 + 16 * H_;
    const float bb0 = fcb[fq * 32 + n16];
    const float bb1 = fcb[fq * 32 + 16 + n16];

    for (int t = 0; t < NSTEP; ++t) {
      const u16* hsrc = (t & 1) ? hb0 : hb1;  // h(t+1)
      if (tid == 0) while (ld_acq(mycnt) < (unsigned)(32 * (t + 1))) {}
      __syncthreads();

      v4f a0 = (v4f){0.f,0.f,0.f,0.f}, a1 = (v4f){0.f,0.f,0.f,0.f};
      const u16* arow = hsrc + (R + wave * 16 + n16) * H_;
      #pragma unroll
      for (int kc = 0; kc < 16; ++kc) {
        int k0 = kc * 32 + q * 8;
        v8s av = *reinterpret_cast<const v8s*>(arow + k0);
        v8s f0 = *reinterpret_cast<const v8s*>(b0 + k0);
        v8s f1 = *reinterpret_cast<const v8s*>(b1 + k0);
        a0 = __builtin_amdgcn_mfma_f32_16x16x32_bf16(av, f0, a0, 0, 0, 0);
        a1 = __builtin_amdgcn_mfma_f32_16x16x32_bf16(av, f1, a1, 0, 0, 0);
      }

      float* dt = dout + (long long)(511 - t) * (B_ * I_);
      #pragma unroll
      for (int r = 0; r < 4; ++r) {
        int row = R + wave * 16 + q * 4 + r;
        float z0 = a0[r] + bb0;
        float o0 = 2.f / (1.f + __expf(-z0)) - 1.f;
        dt[row * I_ + fq * 32 + n16] = o0;
        outb[row * I_ + fq * 32 + n16] = f2b(o0);
        float z1 = a1[r] + bb1;
        float o1 = 2.f / (1.f + __expf(-z1)) - 1.f;
        dt[row * I_ + fq * 32 + 16 + n16] = o1;
        outb[row * I_ + fq * 32 + 16 + n16] = f2b(o1);
      }
      __syncthreads();
      if (tid == 0) arrive(myout);
    }
  }
}

extern "C" void kernel_launch(void* const* d_in, const int* in_sizes, int n_in,
                              void* d_out, int out_size, void* d_ws, size_t ws_size,
                              hipStream_t stream)
{
  const float* x   = (const float*)d_in[0];
  // d_in[1] = enc_hiddens: unused by the reference
  const float* h0  = (const float*)d_in[2];
  const float* c0  = (const float*)d_in[3];
  const float* Wih = (const float*)d_in[4];
  const float* Whh = (const float*)d_in[5];
  const float* bih = (const float*)d_in[6];
  const float* bhh = (const float*)d_in[7];
  const float* fcW = (const float*)d_in[8];
  const float* fcb = (const float*)d_in[9];

  char* p = (char*)d_ws;
  u16*      Wcat  = (u16*)p;      p += 2048LL * 640 * 2;
  u16*      fcWb  = (u16*)p;      p += 128 * 512 * 2;
  float*    bsum  = (float*)p;    p += 2048 * 4;
  u16*      hb0   = (u16*)p;      p += 512 * 512 * 2;
  u16*      hb1   = (u16*)p;      p += 512 * 512 * 2;
  u16*      outb  = (u16*)p;      p += 512 * 128 * 2;
  unsigned* flags = (unsigned*)p; p += 16 * 4;
  float*    dout  = (float*)d_out;

  init_kernel<<<6665, 256, 0, stream>>>(x, h0, Wih, Whh, bih, bhh, fcW,
                                        Wcat, fcWb, bsum, hb0, outb, flags);
  decoder_persist<<<288, 256, 0, stream>>>(Wcat, bsum, fcWb, fcb, c0,
                                           hb0, hb1, outb, dout, flags);
}

// Round 3
// 11321.487 us; speedup vs baseline: 2.6889x; 2.6889x over previous
//
#include <hip/hip_runtime.h>

typedef unsigned short u16;
typedef unsigned int   u32;
typedef unsigned long long u64;
typedef short v8s __attribute__((ext_vector_type(8)));
typedef float v4f __attribute__((ext_vector_type(4)));
typedef float v2f __attribute__((ext_vector_type(2)));

#define B_ 512
#define I_ 128
#define H_ 512
#define KK 640
#define NSTEP 512

union UV { u64 q[2]; v8s v; };

__device__ inline u16 f2b(float x){
  union{float f; unsigned u;} v; v.f = x;
  unsigned r = v.u + 0x7fffu + ((v.u >> 16) & 1u);
  return (u16)(r >> 16);
}

// Relaxed agent-scope data movement: sc0|sc1 -> bypass L1/L2, serialize at L3.
__device__ inline u64 ld64(const u16* p){
  return __hip_atomic_load((const u64*)p, __ATOMIC_RELAXED, __HIP_MEMORY_SCOPE_AGENT);
}
__device__ inline void st32(u16* p, u32 v){
  __hip_atomic_store((u32*)p, v, __ATOMIC_RELAXED, __HIP_MEMORY_SCOPE_AGENT);
}
__device__ inline void st64(u16* p, u64 v){
  __hip_atomic_store((u64*)p, v, __ATOMIC_RELAXED, __HIP_MEMORY_SCOPE_AGENT);
}
__device__ inline u32 pollld(const u32* p){
  return __hip_atomic_load(p, __ATOMIC_RELAXED, __HIP_MEMORY_SCOPE_AGENT);
}
__device__ inline void flag_rel(u32* p, u32 v){
  __hip_atomic_store(p, v, __ATOMIC_RELEASE, __HIP_MEMORY_SCOPE_AGENT);
}
__device__ inline void acq(const u32* p){
  (void)__hip_atomic_load(p, __ATOMIC_ACQUIRE, __HIP_MEMORY_SCOPE_AGENT);
}

// Prep: Wcat[gcol][k] = [W_hh (k<512) | W_ih (k>=512)] bf16 (feedback part LAST),
// fcW bf16, fused bias, h0 bf16, out0 = x[511] bf16, zeroed per-wg flags.
__global__ void init_kernel(const float* __restrict__ x, const float* __restrict__ h0,
    const float* __restrict__ Wih, const float* __restrict__ Whh,
    const float* __restrict__ bih, const float* __restrict__ bhh, const float* __restrict__ fcW,
    u16* __restrict__ Wcat, u16* __restrict__ fcWb, float* __restrict__ bsum,
    u16* __restrict__ hb0, u16* __restrict__ outb, u32* __restrict__ flags)
{
  int idx = blockIdx.x * 256 + threadIdx.x;
  if (idx < 1310720) {                       // Wcat: 2048 x 640, [Whh | Wih]
    int g = idx / 640, k = idx - g * 640;
    float v = (k < 512) ? Whh[g * 512 + k] : Wih[g * 128 + (k - 512)];
    Wcat[idx] = f2b(v);
  } else if (idx < 1376256) {                // fcW bf16: 128 x 512
    int i = idx - 1310720; fcWb[i] = f2b(fcW[i]);
  } else if (idx < 1378304) {                // fused bias: 2048
    int i = idx - 1376256; bsum[i] = bih[i] + bhh[i];
  } else if (idx < 1640448) {                // h init: 512 x 512
    int i = idx - 1378304; hb0[i] = f2b(h0[i]);
  } else if (idx < 1705984) {                // inp init = x[511]: 512 x 128
    int i = idx - 1640448; outb[i] = f2b(x[33488896 + i]);
  } else if (idx < 1707008) {                // hflag[8][64] + oflag[8][64]
    flags[idx - 1705984] = 0u;
  }
}

// Persistent decoder. 288 wgs: wg<256 = gates/cell (mb=wg>>5 owns 64 batch rows,
// nb=wg&31 owns 16 H-cols x 4 gates; wave g = gate g). wg>=256 = fc (4 per group,
// 32 i-cols each), overlapped with next step's gates work.
// Sync: per-producer step-number flags (gates wg -> hflag[mb*64+nb], fc wg ->
// oflag[mb*64+fq]); waiters vector-poll 32 (or 4) flags with one load per
// iteration. All cross-wg data via relaxed agent atomics (through L3, no
// fences); __syncthreads' vmcnt drain orders data stores before flag release.
__global__ __launch_bounds__(256, 2) void decoder_persist(
    const u16* __restrict__ Wcat, const float* __restrict__ bsum,
    const u16* __restrict__ fcWb, const float* __restrict__ fcb,
    const float* __restrict__ c0,
    u16* __restrict__ hb0, u16* __restrict__ hb1, u16* __restrict__ outb,
    float* __restrict__ dout, u32* __restrict__ flags)
{
  __shared__ __align__(16) u16  Alds[64 * 328];   // one k-half (320) + pad
  __shared__ __align__(16) float gbuf[4096];      // gate exchange

  const int tid  = threadIdx.x;
  const int wave = tid >> 6, lane = tid & 63;
  const int n16  = lane & 15, q = lane >> 4;
  u32* hflag = flags;          // [8][64], one 128B line used per group
  u32* oflag = flags + 512;    // [8][64]

  if (blockIdx.x < 256) {
    // ---------------- gates + cell path ----------------
    const int mb = blockIdx.x >> 5, nb = blockIdx.x & 31;
    const int R  = mb * 64;
    u32* hf = hflag + mb * 64;
    u32* of = oflag + mb * 64;

    // Step-invariant W fragments: 20 x v8s = 80 VGPRs
    const u16* wrow = Wcat + (wave * 512 + nb * 16 + n16) * KK + q * 8;
    v8s bfrag[20];
    #pragma unroll
    for (int kc = 0; kc < 20; ++kc)
      bfrag[kc] = *reinterpret_cast<const v8s*>(wrow + kc * 32);

    const float bias = bsum[wave * 512 + nb * 16 + n16];

    // c state: element pair j in {0,1}: e=j*512+tid*2 -> row=e>>4, cols e&15,+1
    float c[4];
    #pragma unroll
    for (int j = 0; j < 2; ++j) {
      int e = j * 512 + tid * 2;
      int row = e >> 4, col = e & 15;
      c[2*j]   = c0[(R + row) * H_ + nb * 16 + col];
      c[2*j+1] = c0[(R + row) * H_ + nb * 16 + col + 1];
    }

    for (int t = 0; t < NSTEP; ++t) {
      const u16* hin  = (t & 1) ? hb1 : hb0;
      u16*       hout = (t & 1) ? hb0 : hb1;

      if (t > 0) {                       // wait: all 32 peers wrote h(t)
        if (wave == 0) {
          if (lane < 32) while (pollld(hf + lane) < (u32)t) {}
          acq(hf);
        }
        __syncthreads();
      }

      v4f acc[4];
      #pragma unroll
      for (int m = 0; m < 4; ++m) acc[m] = (v4f){0.f, 0.f, 0.f, 0.f};

      // ---- stage half1: k in [0,320) from h -> Alds (u64 chunks, batched) ----
      #pragma unroll
      for (int b = 0; b < 2; ++b) {
        u64 tmp[10];
        #pragma unroll
        for (int u = 0; u < 10; ++u) {
          int v = (b * 10 + u) * 256 + tid;
          int row = v / 80, cc = v - row * 80;
          tmp[u] = ld64(hin + (R + row) * H_ + cc * 4);
        }
        #pragma unroll
        for (int u = 0; u < 10; ++u) {
          int v = (b * 10 + u) * 256 + tid;
          int row = v / 80, cc = v - row * 80;
          *reinterpret_cast<u64*>(&Alds[row * 328 + cc * 4]) = tmp[u];
        }
      }
      __syncthreads();
      #pragma unroll
      for (int kc = 0; kc < 10; ++kc) {
        int k0 = kc * 32 + q * 8;
        #pragma unroll
        for (int m = 0; m < 4; ++m) {
          v8s a = *reinterpret_cast<const v8s*>(&Alds[(m * 16 + n16) * 328 + k0]);
          acc[m] = __builtin_amdgcn_mfma_f32_16x16x32_bf16(a, bfrag[kc], acc[m], 0, 0, 0);
        }
      }

      // wait: out(t) ready (fc step t-1 done); barrier also closes half1 LDS reads
      if (wave == 0) {
        if (lane < 4) while (pollld(of + lane) < (u32)t) {}
        acq(of);
      }
      __syncthreads();

      // ---- stage half2: h k in [320,512) -> chunks 0..47; out -> 48..79 ----
      {
        u64 tmp[12];
        #pragma unroll
        for (int u = 0; u < 12; ++u) {
          int v = u * 256 + tid;
          int row = v / 48, cc = v - row * 48;
          tmp[u] = ld64(hin + (R + row) * H_ + 320 + cc * 4);
        }
        #pragma unroll
        for (int u = 0; u < 12; ++u) {
          int v = u * 256 + tid;
          int row = v / 48, cc = v - row * 48;
          *reinterpret_cast<u64*>(&Alds[row * 328 + cc * 4]) = tmp[u];
        }
      }
      {
        u64 tmp[8];
        #pragma unroll
        for (int u = 0; u < 8; ++u) {
          int v = u * 256 + tid;
          int row = v >> 5, cc = v & 31;
          tmp[u] = ld64(outb + (R + row) * I_ + cc * 4);
        }
        #pragma unroll
        for (int u = 0; u < 8; ++u) {
          int v = u * 256 + tid;
          int row = v >> 5, cc = v & 31;
          *reinterpret_cast<u64*>(&Alds[row * 328 + 192 + cc * 4]) = tmp[u];
        }
      }
      __syncthreads();
      #pragma unroll
      for (int kc = 0; kc < 10; ++kc) {
        int k0 = kc * 32 + q * 8;
        #pragma unroll
        for (int m = 0; m < 4; ++m) {
          v8s a = *reinterpret_cast<const v8s*>(&Alds[(m * 16 + n16) * 328 + k0]);
          acc[m] = __builtin_amdgcn_mfma_f32_16x16x32_bf16(a, bfrag[10 + kc], acc[m], 0, 0, 0);
        }
      }

      // ---- activations -> LDS exchange ----
      #pragma unroll
      for (int m = 0; m < 4; ++m) {
        #pragma unroll
        for (int r = 0; r < 4; ++r) {
          float z = acc[m][r] + bias;
          float a = (wave == 2) ? tanhf(z) : 1.f / (1.f + __expf(-z));
          gbuf[wave * 1024 + (m * 16 + q * 4 + r) * 16 + n16] = a;
        }
      }
      __syncthreads();

      // ---- cell: c in regs, h_new packed u32 -> L3 ----
      #pragma unroll
      for (int j = 0; j < 2; ++j) {
        int e = j * 512 + tid * 2;
        int row = e >> 4, col = e & 15;
        v2f ig = *reinterpret_cast<const v2f*>(&gbuf[       row * 16 + col]);
        v2f fg = *reinterpret_cast<const v2f*>(&gbuf[1024 + row * 16 + col]);
        v2f gg = *reinterpret_cast<const v2f*>(&gbuf[2048 + row * 16 + col]);
        v2f og = *reinterpret_cast<const v2f*>(&gbuf[3072 + row * 16 + col]);
        float cn0 = fg[0] * c[2*j]   + ig[0] * gg[0];
        float cn1 = fg[1] * c[2*j+1] + ig[1] * gg[1];
        c[2*j] = cn0; c[2*j+1] = cn1;
        u32 packed = (u32)f2b(og[0] * tanhf(cn0)) | ((u32)f2b(og[1] * tanhf(cn1)) << 16);
        st32(hout + (R + row) * H_ + nb * 16 + col, packed);
      }
      __syncthreads();                    // vmcnt drain: h stores acked at L3
      if (tid == 0) flag_rel(hf + nb, (u32)(t + 1));
    }
  } else {
    // ---------------- fc path (overlapped) ----------------
    const int f  = blockIdx.x - 256;
    const int mb = f >> 2, fq = f & 3;
    const int R  = mb * 64;
    u32* hf = hflag + mb * 64;
    u32* of = oflag + mb * 64;
    u16* olds = (u16*)Alds;               // 64 x 32 u16 out staging

    const u16* b0 = fcWb + (fq * 32 + n16) * H_;   // plain loads (immutable)
    const u16* b1 = b0 + 16 * H_;
    const float bb0 = fcb[fq * 32 + n16];
    const float bb1 = fcb[fq * 32 + 16 + n16];

    for (int t = 0; t < NSTEP; ++t) {
      const u16* hsrc = (t & 1) ? hb0 : hb1;       // h(t+1)
      if (wave == 0) {
        if (lane < 32) while (pollld(hf + lane) < (u32)(t + 1)) {}
        acq(hf);
      }
      __syncthreads();

      // prefetch this lane's A-row fragments: 32 independent u64 L3 loads
      u64 ha[32];
      const u16* hrow = hsrc + (R + wave * 16 + n16) * H_;
      #pragma unroll
      for (int kc = 0; kc < 16; ++kc) {
        ha[2*kc]   = ld64(hrow + kc * 32 + q * 8);
        ha[2*kc+1] = ld64(hrow + kc * 32 + q * 8 + 4);
      }

      v4f a0 = (v4f){0.f,0.f,0.f,0.f}, a1 = (v4f){0.f,0.f,0.f,0.f};
      #pragma unroll
      for (int kc = 0; kc < 16; ++kc) {
        int k0 = kc * 32 + q * 8;
        UV uv; uv.q[0] = ha[2*kc]; uv.q[1] = ha[2*kc+1];
        v8s f0 = *reinterpret_cast<const v8s*>(b0 + k0);
        v8s f1 = *reinterpret_cast<const v8s*>(b1 + k0);
        a0 = __builtin_amdgcn_mfma_f32_16x16x32_bf16(uv.v, f0, a0, 0, 0, 0);
        a1 = __builtin_amdgcn_mfma_f32_16x16x32_bf16(uv.v, f1, a1, 0, 0, 0);
      }

      float* dt = dout + (long long)(511 - t) * (B_ * I_);
      #pragma unroll
      for (int r = 0; r < 4; ++r) {
        int lrow = wave * 16 + q * 4 + r;
        int grow = R + lrow;
        float o0 = 2.f / (1.f + __expf(-(a0[r] + bb0))) - 1.f;
        __builtin_nontemporal_store(o0, &dt[grow * I_ + fq * 32 + n16]);
        olds[lrow * 32 + n16] = f2b(o0);
        float o1 = 2.f / (1.f + __expf(-(a1[r] + bb1))) - 1.f;
        __builtin_nontemporal_store(o1, &dt[grow * I_ + fq * 32 + 16 + n16]);
        olds[lrow * 32 + 16 + n16] = f2b(o1);
      }
      __syncthreads();
      // flush out tile (64x32) as packed u64 relaxed stores -> L3
      #pragma unroll
      for (int i2 = 0; i2 < 2; ++i2) {
        int idx = i2 * 256 + tid;
        int row = idx >> 3, seg = idx & 7;
        st64(outb + (R + row) * I_ + fq * 32 + seg * 4,
             *reinterpret_cast<const u64*>(&olds[row * 32 + seg * 4]));
      }
      __syncthreads();                    // vmcnt drain
      if (tid == 0) flag_rel(of + fq, (u32)(t + 1));
    }
  }
}

extern "C" void kernel_launch(void* const* d_in, const int* in_sizes, int n_in,
                              void* d_out, int out_size, void* d_ws, size_t ws_size,
                              hipStream_t stream)
{
  const float* x   = (const float*)d_in[0];
  // d_in[1] = enc_hiddens: unused by the reference
  const float* h0  = (const float*)d_in[2];
  const float* c0  = (const float*)d_in[3];
  const float* Wih = (const float*)d_in[4];
  const float* Whh = (const float*)d_in[5];
  const float* bih = (const float*)d_in[6];
  const float* bhh = (const float*)d_in[7];
  const float* fcW = (const float*)d_in[8];
  const float* fcb = (const float*)d_in[9];

  char* p = (char*)d_ws;
  u16*   Wcat  = (u16*)p;   p += 2048LL * 640 * 2;
  u16*   fcWb  = (u16*)p;   p += 128 * 512 * 2;
  float* bsum  = (float*)p; p += 2048 * 4;
  u16*   hb0   = (u16*)p;   p += 512 * 512 * 2;
  u16*   hb1   = (u16*)p;   p += 512 * 512 * 2;
  u16*   outb  = (u16*)p;   p += 512 * 128 * 2;
  u32*   flags = (u32*)p;   p += 1024 * 4;
  float* dout  = (float*)d_out;

  init_kernel<<<6669, 256, 0, stream>>>(x, h0, Wih, Whh, bih, bhh, fcW,
                                        Wcat, fcWb, bsum, hb0, outb, flags);
  decoder_persist<<<288, 256, 0, stream>>>(Wcat, bsum, fcWb, fcb, c0,
                                           hb0, hb1, outb, dout, flags);
}

// Round 4
// 5936.400 us; speedup vs baseline: 5.1281x; 1.9071x over previous
//
#include <hip/hip_runtime.h>

typedef unsigned short u16;
typedef unsigned int   u32;
typedef unsigned long long u64;
typedef short v8s __attribute__((ext_vector_type(8)));
typedef float v4f __attribute__((ext_vector_type(4)));
typedef float v2f __attribute__((ext_vector_type(2)));

#define B_ 512
#define I_ 128
#define H_ 512
#define KK 640
#define NSTEP 512
#define AST 648   // A-tile row stride, elements (1296 B = 324 dw, 324%32=4 -> good spread)

__device__ inline u16 f2b(float x){
  union{float f; unsigned u;} v; v.f = x;
  unsigned r = v.u + 0x7fffu + ((v.u >> 16) & 1u);
  return (u16)(r >> 16);
}

// All cross-wg traffic: relaxed agent-scope atomics -> sc0 sc1, L3 = coherence
// point. NO acquire/release anywhere in the loop (they lower to buffer_inv/wbl2
// sc1 = full L2 invalidate per step = R3's 2.6 MB/step W refetch).
__device__ inline u64 ld64(const u16* p){
  return __hip_atomic_load((const u64*)p, __ATOMIC_RELAXED, __HIP_MEMORY_SCOPE_AGENT);
}
__device__ inline void st32(u16* p, u32 v){
  __hip_atomic_store((u32*)p, v, __ATOMIC_RELAXED, __HIP_MEMORY_SCOPE_AGENT);
}
__device__ inline u32 fpoll(const u32* p){
  return __hip_atomic_load(p, __ATOMIC_RELAXED, __HIP_MEMORY_SCOPE_AGENT);
}
__device__ inline void fst(u32* p, u32 v){
  __hip_atomic_store(p, v, __ATOMIC_RELAXED, __HIP_MEMORY_SCOPE_AGENT);
}

// Prep: Wcat[gcol][k] = [W_hh (k<512) | W_ih (k>=512)] bf16, fcW bf16, fused
// bias, h0 bf16, out0 = x[511] bf16, zeroed flags. Re-runs every call.
__global__ void init_kernel(const float* __restrict__ x, const float* __restrict__ h0,
    const float* __restrict__ Wih, const float* __restrict__ Whh,
    const float* __restrict__ bih, const float* __restrict__ bhh, const float* __restrict__ fcW,
    u16* __restrict__ Wcat, u16* __restrict__ fcWb, float* __restrict__ bsum,
    u16* __restrict__ hb0, u16* __restrict__ outb, u32* __restrict__ flags)
{
  int idx = blockIdx.x * 256 + threadIdx.x;
  if (idx < 1310720) {                       // Wcat: 2048 x 640, [Whh | Wih]
    int g = idx / 640, k = idx - g * 640;
    float v = (k < 512) ? Whh[g * 512 + k] : Wih[g * 128 + (k - 512)];
    Wcat[idx] = f2b(v);
  } else if (idx < 1376256) {                // fcW bf16: 128 x 512
    int i = idx - 1310720; fcWb[i] = f2b(fcW[i]);
  } else if (idx < 1378304) {                // fused bias: 2048
    int i = idx - 1376256; bsum[i] = bih[i] + bhh[i];
  } else if (idx < 1640448) {                // h init: 512 x 512
    int i = idx - 1378304; hb0[i] = f2b(h0[i]);
  } else if (idx < 1705984) {                // inp init = x[511]: 512 x 128
    int i = idx - 1640448; outb[i] = f2b(x[33488896 + i]);
  } else if (idx < 1706240) {                // hflag[8][32]
    flags[idx - 1705984] = 0u;
  }
}

// Persistent decoder, grid = 256 (1 wg/CU, all co-resident). 8 groups x 32 wgs.
// wg (mb,nb): gates for rows mb*64..+64, gate-cols nb*16..+16 per gate (wave =
// gate), PLUS a redundant local fc for the whole group's 64 rows (removes the
// fc wgs and the out(t) exchange entirely -> ONE L3 handoff per step: h).
// Step t: wait h(t) -> gather h-tile to LDS -> fc: out(t-1)=act(h(t)@fcW^T)
// into LDS A-tile k in [512,640) (+ dout slice) -> gates GEMM (k=640) -> cell
// -> h(t+1) st32 sc0sc1 -> barrier (vmcnt drain) -> flag t+1. Tail iteration
// t=512 computes the final out(511).
__global__ __launch_bounds__(256, 1) void decoder_persist(
    const u16* __restrict__ Wcat, const float* __restrict__ bsum,
    const u16* __restrict__ fcWb, const float* __restrict__ fcb,
    const float* __restrict__ c0,
    u16* __restrict__ hb0, u16* __restrict__ hb1, const u16* __restrict__ outb,
    float* __restrict__ dout, u32* __restrict__ flags)
{
  __shared__ __align__(16) u16  Alds[64 * AST];   // 64 x (512 h | 128 out | 8 pad)
  __shared__ __align__(16) float gbuf[4096];      // gate exchange

  const int tid  = threadIdx.x;
  const int wave = tid >> 6, lane = tid & 63;
  const int n16  = lane & 15, q = lane >> 4;
  const int mb   = blockIdx.x >> 5, nb = blockIdx.x & 31;
  const int R    = mb * 64;
  u32* hf = flags + mb * 32;

  // ---- resident weights ----
  const u16* wrow = Wcat + (wave * 512 + nb * 16 + n16) * KK + q * 8;
  v8s bfrag[20];
  #pragma unroll
  for (int kc = 0; kc < 20; ++kc)
    bfrag[kc] = *reinterpret_cast<const v8s*>(wrow + kc * 32);

  v8s ffrag[2][16];
  #pragma unroll
  for (int j = 0; j < 2; ++j) {
    const u16* fr = fcWb + (wave * 32 + j * 16 + n16) * H_ + q * 8;
    #pragma unroll
    for (int kc = 0; kc < 16; ++kc)
      ffrag[j][kc] = *reinterpret_cast<const v8s*>(fr + kc * 32);
  }

  const float gbias = bsum[wave * 512 + nb * 16 + n16];
  const float fb0 = fcb[wave * 32 + n16];
  const float fb1 = fcb[wave * 32 + 16 + n16];

  // dout slice ownership: wg nb writes out cols [4nb, 4nb+4)
  const int jsel = (nb >> 2) & 1, nbase = (nb & 3) * 4;
  const bool dopred = (wave == (nb >> 3)) && (n16 >= nbase) && (n16 < nbase + 4);

  // c state: pair j: e = j*512 + tid*2 -> row=e>>4, cols (e&15, e&15+1)
  float c[4];
  #pragma unroll
  for (int j = 0; j < 2; ++j) {
    int e = j * 512 + tid * 2;
    int row = e >> 4, col = e & 15;
    c[2*j]   = c0[(R + row) * H_ + nb * 16 + col];
    c[2*j+1] = c0[(R + row) * H_ + nb * 16 + col + 1];
  }

  for (int t = 0; t <= NSTEP; ++t) {
    const u16* hsrc = (t & 1) ? hb1 : hb0;

    if (t > 0 && wave == 0 && lane < 32) {
      while (fpoll(hf + lane) < (u32)t) {}
    }
    __asm__ volatile("" ::: "memory");
    __syncthreads();

    // ---- gather h(t): 64 x 512 bf16 -> LDS, 2 batches x 16 u64/thread ----
    #pragma unroll
    for (int b = 0; b < 2; ++b) {
      u64 tmp[16];
      #pragma unroll
      for (int u = 0; u < 16; ++u) {
        int v = (b * 16 + u) * 256 + tid;
        int row = v >> 7, cc = v & 127;
        tmp[u] = ld64(hsrc + (R + row) * H_ + cc * 4);
      }
      #pragma unroll
      for (int u = 0; u < 16; ++u) {
        int v = (b * 16 + u) * 256 + tid;
        int row = v >> 7, cc = v & 127;
        *reinterpret_cast<u64*>(&Alds[row * AST + cc * 4]) = tmp[u];
      }
    }
    if (t == 0) {                       // out(-1) = x[511] (preconverted)
      u64 tmp[8];
      #pragma unroll
      for (int u = 0; u < 8; ++u) {
        int v = u * 256 + tid;
        int row = v >> 5, cc = v & 31;
        tmp[u] = ld64(outb + (R + row) * I_ + cc * 4);
      }
      #pragma unroll
      for (int u = 0; u < 8; ++u) {
        int v = u * 256 + tid;
        int row = v >> 5, cc = v & 31;
        *reinterpret_cast<u64*>(&Alds[row * AST + 512 + cc * 4]) = tmp[u];
      }
    }
    __syncthreads();

    if (t > 0) {
      // ---- local fc: out(t-1) = 2*sigmoid(h(t) @ fcW^T + fcb) - 1 ----
      v4f fa[4][2];
      #pragma unroll
      for (int m = 0; m < 4; ++m) { fa[m][0] = (v4f){0,0,0,0}; fa[m][1] = (v4f){0,0,0,0}; }
      #pragma unroll
      for (int kc = 0; kc < 16; ++kc) {
        int k0 = kc * 32 + q * 8;
        #pragma unroll
        for (int m = 0; m < 4; ++m) {
          v8s a = *reinterpret_cast<const v8s*>(&Alds[(m * 16 + n16) * AST + k0]);
          fa[m][0] = __builtin_amdgcn_mfma_f32_16x16x32_bf16(a, ffrag[0][kc], fa[m][0], 0, 0, 0);
          fa[m][1] = __builtin_amdgcn_mfma_f32_16x16x32_bf16(a, ffrag[1][kc], fa[m][1], 0, 0, 0);
        }
      }
      float* dt = dout + (long long)(NSTEP - t) * (B_ * I_);
      #pragma unroll
      for (int m = 0; m < 4; ++m) {
        #pragma unroll
        for (int j = 0; j < 2; ++j) {
          float fbias = j ? fb1 : fb0;
          int col = wave * 32 + j * 16 + n16;
          #pragma unroll
          for (int r = 0; r < 4; ++r) {
            int row = m * 16 + q * 4 + r;
            float o = 2.f / (1.f + __expf(-(fa[m][j][r] + fbias))) - 1.f;
            Alds[row * AST + 512 + col] = f2b(o);          // feedback into A-tile
            if (dopred && j == jsel)
              __builtin_nontemporal_store(o, dt + (R + row) * I_ + col);
          }
        }
      }
    }

    if (t < NSTEP) {
      __syncthreads();                  // out region ready for gates

      // ---- gates GEMM: k = 640 over [h | out] ----
      v4f acc[4];
      #pragma unroll
      for (int m = 0; m < 4; ++m) acc[m] = (v4f){0,0,0,0};
      #pragma unroll
      for (int kc = 0; kc < 20; ++kc) {
        int k0 = kc * 32 + q * 8;
        #pragma unroll
        for (int m = 0; m < 4; ++m) {
          v8s a = *reinterpret_cast<const v8s*>(&Alds[(m * 16 + n16) * AST + k0]);
          acc[m] = __builtin_amdgcn_mfma_f32_16x16x32_bf16(a, bfrag[kc], acc[m], 0, 0, 0);
        }
      }
      #pragma unroll
      for (int m = 0; m < 4; ++m) {
        #pragma unroll
        for (int r = 0; r < 4; ++r) {
          float z = acc[m][r] + gbias;
          float a = (wave == 2) ? tanhf(z) : 1.f / (1.f + __expf(-z));
          gbuf[wave * 1024 + (m * 16 + q * 4 + r) * 16 + n16] = a;
        }
      }
      __syncthreads();

      // ---- cell: c in regs, h(t+1) packed u32 -> L3 ----
      u16* hdst = (t & 1) ? hb0 : hb1;
      #pragma unroll
      for (int j = 0; j < 2; ++j) {
        int e = j * 512 + tid * 2;
        int row = e >> 4, col = e & 15;
        v2f ig = *reinterpret_cast<const v2f*>(&gbuf[       row * 16 + col]);
        v2f fg = *reinterpret_cast<const v2f*>(&gbuf[1024 + row * 16 + col]);
        v2f gg = *reinterpret_cast<const v2f*>(&gbuf[2048 + row * 16 + col]);
        v2f og = *reinterpret_cast<const v2f*>(&gbuf[3072 + row * 16 + col]);
        float cn0 = fg[0] * c[2*j]   + ig[0] * gg[0];
        float cn1 = fg[1] * c[2*j+1] + ig[1] * gg[1];
        c[2*j] = cn0; c[2*j+1] = cn1;
        u32 packed = (u32)f2b(og[0] * tanhf(cn0)) | ((u32)f2b(og[1] * tanhf(cn1)) << 16);
        st32(hdst + (R + row) * H_ + nb * 16 + col, packed);
      }
      __syncthreads();                  // vmcnt(0) drain: h stores acked at L3
      __asm__ volatile("" ::: "memory");
      if (tid == 0) fst(hf + nb, (u32)(t + 1));
    }
  }
}

extern "C" void kernel_launch(void* const* d_in, const int* in_sizes, int n_in,
                              void* d_out, int out_size, void* d_ws, size_t ws_size,
                              hipStream_t stream)
{
  const float* x   = (const float*)d_in[0];
  // d_in[1] = enc_hiddens: unused by the reference
  const float* h0  = (const float*)d_in[2];
  const float* c0  = (const float*)d_in[3];
  const float* Wih = (const float*)d_in[4];
  const float* Whh = (const float*)d_in[5];
  const float* bih = (const float*)d_in[6];
  const float* bhh = (const float*)d_in[7];
  const float* fcW = (const float*)d_in[8];
  const float* fcb = (const float*)d_in[9];

  char* p = (char*)d_ws;
  u16*   Wcat  = (u16*)p;   p += 2048LL * 640 * 2;
  u16*   fcWb  = (u16*)p;   p += 128 * 512 * 2;
  float* bsum  = (float*)p; p += 2048 * 4;
  u16*   hb0   = (u16*)p;   p += 512 * 512 * 2;
  u16*   hb1   = (u16*)p;   p += 512 * 512 * 2;
  u16*   outb  = (u16*)p;   p += 512 * 128 * 2;
  u32*   flags = (u32*)p;   p += 256 * 4;
  float* dout  = (float*)d_out;

  init_kernel<<<6666, 256, 0, stream>>>(x, h0, Wih, Whh, bih, bhh, fcW,
                                        Wcat, fcWb, bsum, hb0, outb, flags);
  decoder_persist<<<256, 256, 0, stream>>>(Wcat, bsum, fcWb, fcb, c0,
                                           hb0, hb1, outb, dout, flags);
}